// Round 1
// baseline (512.611 us; speedup 1.0000x reference)
//
#include <hip/hip_runtime.h>

#define NN 100000
#define NE 600000
#define DD 128

// ---------------- CSR build ----------------

__global__ __launch_bounds__(256) void zero_kernel(int* __restrict__ p, int n) {
  int i = blockIdx.x * 256 + threadIdx.x;
  if (i < n) p[i] = 0;
}

__global__ __launch_bounds__(256) void count_deg(const int* __restrict__ dst, int* __restrict__ cnt) {
  int e = blockIdx.x * 256 + threadIdx.x;
  if (e < NE) atomicAdd(&cnt[dst[e]], 1);
}

__global__ __launch_bounds__(1024) void scan_partial(const int* __restrict__ cnt,
                                                     int* __restrict__ rowptr,
                                                     int* __restrict__ bsum) {
  __shared__ int tmp[2][1024];
  int t = threadIdx.x;
  int g = blockIdx.x * 1024 + t;
  int v = (g < NN) ? cnt[g] : 0;
  tmp[0][t] = v;
  __syncthreads();
  int pb = 0;
  for (int off = 1; off < 1024; off <<= 1) {
    int nv = tmp[pb][t] + ((t >= off) ? tmp[pb][t - off] : 0);
    tmp[1 - pb][t] = nv;
    pb ^= 1;
    __syncthreads();
  }
  int incl = tmp[pb][t];
  if (g < NN) rowptr[g] = incl - v;   // exclusive
  if (t == 1023) bsum[blockIdx.x] = incl;
}

__global__ void scan_sums(int* __restrict__ bsum, int nb) {
  if (threadIdx.x == 0 && blockIdx.x == 0) {
    int run = 0;
    for (int j = 0; j < nb; ++j) { int tv = bsum[j]; bsum[j] = run; run += tv; }
  }
}

__global__ __launch_bounds__(256) void scan_add(int* __restrict__ rowptr, const int* __restrict__ bsum) {
  int g = blockIdx.x * 256 + threadIdx.x;
  if (g < NN) rowptr[g] += bsum[g >> 10];
  if (g == 0) rowptr[NN] = NE;
}

__global__ __launch_bounds__(256) void fill_csr(const int* __restrict__ src, const int* __restrict__ dst,
                                                const int* __restrict__ rowptr, int* __restrict__ cur,
                                                int* __restrict__ srcidx) {
  int e = blockIdx.x * 256 + threadIdx.x;
  if (e < NE) {
    int d = dst[e];
    int pos = atomicAdd(&cur[d], 1);
    srcidx[rowptr[d] + pos] = src[e];
  }
}

// ---------------- aggregation: gather-sum via CSR (no fp32 atomics) ----------------
// 32-lane half-wave per node; each lane owns one float4 (4 features) of the 128-wide row.

__global__ __launch_bounds__(256) void aggregate(const float* __restrict__ y,
                                                 const int* __restrict__ rowptr,
                                                 const int* __restrict__ srcidx,
                                                 float* __restrict__ agg) {
  int grp  = (int)((blockIdx.x * 256 + threadIdx.x) >> 5);
  int lane = threadIdx.x & 31;
  if (grp >= NN) return;
  int beg = rowptr[grp], end = rowptr[grp + 1];
  float4 a0 = make_float4(0.f, 0.f, 0.f, 0.f);
  float4 a1 = make_float4(0.f, 0.f, 0.f, 0.f);
  int j = beg;
  for (; j + 2 <= end; j += 2) {        // unroll x2, two acc chains for ILP
    int s0 = srcidx[j], s1 = srcidx[j + 1];
    float4 v0 = *(const float4*)(y + (size_t)s0 * DD + lane * 4);
    float4 v1 = *(const float4*)(y + (size_t)s1 * DD + lane * 4);
    a0.x += v0.x; a0.y += v0.y; a0.z += v0.z; a0.w += v0.w;
    a1.x += v1.x; a1.y += v1.y; a1.z += v1.z; a1.w += v1.w;
  }
  if (j < end) {
    int s0 = srcidx[j];
    float4 v0 = *(const float4*)(y + (size_t)s0 * DD + lane * 4);
    a0.x += v0.x; a0.y += v0.y; a0.z += v0.z; a0.w += v0.w;
  }
  float4 o = make_float4(a0.x + a1.x, a0.y + a1.y, a0.z + a1.z, a0.w + a1.w);
  *(float4*)(agg + (size_t)grp * DD + lane * 4) = o;
}

// ---------------- GEMM: C[nrows,128] = act(A[nrows,128] @ W[128,128] + b) ----------------
// fp32 vector FMA (no fp32 MFMA on CDNA4). BM=64, BK=32, 256 thr, 4x8 microtile.
// LDS ~25KB -> 6 blocks/CU. Inner loop: 3x ds_read_b128 + 32 v_fma_f32 per k.

template <bool RELU>
__global__ __launch_bounds__(256) void gemm128(const float* __restrict__ A,
                                               const float* __restrict__ Wm,
                                               const float* __restrict__ bias,
                                               float* __restrict__ C, int nrows) {
  __shared__ float AsT[32][68];   // [k][m], pad 68: b128-aligned, 2-way-max on reads
  __shared__ float Ws[32][128];   // [k][c]
  int t  = threadIdx.x;
  int tx = t & 15;                // col group: 8 cols at tx*8
  int ty = t >> 4;                // row group: 4 rows at ty*4
  int m0 = blockIdx.x * 64;
  float acc[4][8];
  #pragma unroll
  for (int r = 0; r < 4; ++r)
    #pragma unroll
    for (int c = 0; c < 8; ++c) acc[r][c] = 0.f;

  for (int kb = 0; kb < 4; ++kb) {
    // stage A chunk 64x32, transposed into AsT[k][m]
    #pragma unroll
    for (int i = 0; i < 2; ++i) {
      int q = t + i * 256;              // 0..511
      int m = q >> 3, k4 = q & 7;
      int row = m0 + m; if (row >= nrows) row = nrows - 1;  // clamp (stores are guarded)
      float4 v = *(const float4*)(A + (size_t)row * DD + kb * 32 + k4 * 4);
      AsT[k4 * 4 + 0][m] = v.x;
      AsT[k4 * 4 + 1][m] = v.y;
      AsT[k4 * 4 + 2][m] = v.z;
      AsT[k4 * 4 + 3][m] = v.w;
    }
    // stage W chunk 32x128
    #pragma unroll
    for (int i = 0; i < 4; ++i) {
      int q = t + i * 256;              // 0..1023
      int kk = q >> 5, c4 = q & 31;
      *(float4*)(&Ws[kk][c4 * 4]) = *(const float4*)(Wm + (size_t)(kb * 32 + kk) * DD + c4 * 4);
    }
    __syncthreads();
    #pragma unroll
    for (int k = 0; k < 32; ++k) {
      float4 av = *(const float4*)(&AsT[k][ty * 4]);
      float4 w0 = *(const float4*)(&Ws[k][tx * 8]);
      float4 w1 = *(const float4*)(&Ws[k][tx * 8 + 4]);
      float a[4] = {av.x, av.y, av.z, av.w};
      float w[8] = {w0.x, w0.y, w0.z, w0.w, w1.x, w1.y, w1.z, w1.w};
      #pragma unroll
      for (int r = 0; r < 4; ++r)
        #pragma unroll
        for (int c = 0; c < 8; ++c) acc[r][c] += a[r] * w[c];
    }
    __syncthreads();
  }

  int c0 = tx * 8;
  float4 b0 = *(const float4*)(bias + c0);
  float4 b1 = *(const float4*)(bias + c0 + 4);
  float bb[8] = {b0.x, b0.y, b0.z, b0.w, b1.x, b1.y, b1.z, b1.w};
  #pragma unroll
  for (int r = 0; r < 4; ++r) {
    int row = m0 + ty * 4 + r;
    if (row < nrows) {
      float o[8];
      #pragma unroll
      for (int c = 0; c < 8; ++c) {
        float v = acc[r][c] + bb[c];
        o[c] = RELU ? fmaxf(v, 0.f) : v;
      }
      *(float4*)(C + (size_t)row * DD + c0)     = make_float4(o[0], o[1], o[2], o[3]);
      *(float4*)(C + (size_t)row * DD + c0 + 4) = make_float4(o[4], o[5], o[6], o[7]);
    }
  }
}

// ---------------- launch ----------------

extern "C" void kernel_launch(void* const* d_in, const int* in_sizes, int n_in,
                              void* d_out, int out_size, void* d_ws, size_t ws_size,
                              hipStream_t stream) {
  const float* x     = (const float*)d_in[0];
  const int*   ei    = (const int*)d_in[1];
  const float* W     = (const float*)d_in[2];
  const float* b     = (const float*)d_in[3];
  const float* W_out = (const float*)d_in[4];
  const float* b_out = (const float*)d_in[5];
  float*       out   = (float*)d_out;

  const int* src = ei;        // edge_index[0]
  const int* dst = ei + NE;   // edge_index[1]

  // workspace layout (256B aligned)
  char* ws = (char*)d_ws;
  int*   rowptr = (int*)(ws + 0);            // (NN+1) ints -> 400128 B
  int*   cnt    = (int*)(ws + 400128);       // NN ints     -> 400128 B
  int*   bsum   = (int*)(ws + 800256);       // 512 ints    -> 2048 B
  int*   srcidx = (int*)(ws + 802304);       // NE ints     -> 2400000 B
  float* bufA   = (float*)(ws + 3202304);    // NN*DD f32   -> 51200000 B
  float* bufB   = (float*)(ws + 54402304);   // NN*DD f32
  // total: 105,602,304 B

  const int nb_scan = (NN + 1023) / 1024;    // 98

  // CSR build (edge_index is identical every call; ws is re-poisoned so rebuild)
  zero_kernel<<<(NN + 255) / 256, 256, 0, stream>>>(cnt, NN);
  count_deg<<<(NE + 255) / 256, 256, 0, stream>>>(dst, cnt);
  scan_partial<<<nb_scan, 1024, 0, stream>>>(cnt, rowptr, bsum);
  scan_sums<<<1, 64, 0, stream>>>(bsum, nb_scan);
  scan_add<<<(NN + 255) / 256, 256, 0, stream>>>(rowptr, bsum);
  zero_kernel<<<(NN + 255) / 256, 256, 0, stream>>>(cnt, NN);
  fill_csr<<<(NE + 255) / 256, 256, 0, stream>>>(src, dst, rowptr, cnt, srcidx);

  const int aggBlocks  = (NN * 32 + 255) / 256;   // 12500
  const int gemmBlocks = (NN + 63) / 64;          // 1563

  // layer 1
  aggregate<<<aggBlocks, 256, 0, stream>>>(x, rowptr, srcidx, bufA);
  gemm128<true><<<gemmBlocks, 256, 0, stream>>>(bufA, W, b, bufB, NN);
  // layer 2
  aggregate<<<aggBlocks, 256, 0, stream>>>(bufB, rowptr, srcidx, bufA);
  gemm128<true><<<gemmBlocks, 256, 0, stream>>>(bufA, W, b, bufB, NN);
  // layer 3
  aggregate<<<aggBlocks, 256, 0, stream>>>(bufB, rowptr, srcidx, bufA);
  gemm128<true><<<gemmBlocks, 256, 0, stream>>>(bufA, W, b, bufB, NN);
  // output projection
  gemm128<false><<<gemmBlocks, 256, 0, stream>>>(bufB, W_out, b_out, out, NN);
}

// Round 2
// 413.602 us; speedup vs baseline: 1.2394x; 1.2394x over previous
//
#include <hip/hip_runtime.h>

#define NN 100000
#define NE 600000
#define DD 128

typedef __attribute__((ext_vector_type(8))) short bf16x8;   // 8 bf16 in 4 VGPRs
typedef __attribute__((ext_vector_type(4))) float f32x4;

__device__ __forceinline__ ushort f2bf(float f) {   // round-to-nearest-even
  uint u = __float_as_uint(f);
  return (ushort)((u + 0x7FFF + ((u >> 16) & 1)) >> 16);
}
__device__ __forceinline__ float bf2f(ushort h) { return __uint_as_float(((uint)h) << 16); }

// ---------------- CSR build ----------------

__global__ __launch_bounds__(256) void zero_kernel(int* __restrict__ p, int n) {
  int i = blockIdx.x * 256 + threadIdx.x;
  if (i < n) p[i] = 0;
}

__global__ __launch_bounds__(256) void count_deg(const int* __restrict__ dst, int* __restrict__ cnt) {
  int e = blockIdx.x * 256 + threadIdx.x;
  if (e < NE) atomicAdd(&cnt[dst[e]], 1);
}

__global__ __launch_bounds__(1024) void scan_partial(const int* __restrict__ cnt,
                                                     int* __restrict__ rowptr,
                                                     int* __restrict__ bsum) {
  __shared__ int tmp[2][1024];
  int t = threadIdx.x;
  int g = blockIdx.x * 1024 + t;
  int v = (g < NN) ? cnt[g] : 0;
  tmp[0][t] = v;
  __syncthreads();
  int pb = 0;
  for (int off = 1; off < 1024; off <<= 1) {
    int nv = tmp[pb][t] + ((t >= off) ? tmp[pb][t - off] : 0);
    tmp[1 - pb][t] = nv;
    pb ^= 1;
    __syncthreads();
  }
  int incl = tmp[pb][t];
  if (g < NN) rowptr[g] = incl - v;   // exclusive
  if (t == 1023) bsum[blockIdx.x] = incl;
}

__global__ __launch_bounds__(128) void scan_sums(int* __restrict__ bsum, int nb) {
  __shared__ int s[128];
  int t = threadIdx.x;
  s[t] = (t < nb) ? bsum[t] : 0;
  __syncthreads();
  if (t == 0) {
    int run = 0;
    for (int j = 0; j < nb; ++j) { int v = s[j]; s[j] = run; run += v; }
  }
  __syncthreads();
  if (t < nb) bsum[t] = s[t];
}

__global__ __launch_bounds__(256) void scan_add(int* __restrict__ rowptr, const int* __restrict__ bsum) {
  int g = blockIdx.x * 256 + threadIdx.x;
  if (g < NN) rowptr[g] += bsum[g >> 10];
  if (g == 0) rowptr[NN] = NE;
}

__global__ __launch_bounds__(256) void fill_csr(const int* __restrict__ src, const int* __restrict__ dst,
                                                const int* __restrict__ rowptr, int* __restrict__ cur,
                                                int* __restrict__ srcidx) {
  int e = blockIdx.x * 256 + threadIdx.x;
  if (e < NE) {
    int d = dst[e];
    int pos = atomicAdd(&cur[d], 1);
    srcidx[rowptr[d] + pos] = src[e];
  }
}

// ---------------- W prep: fp32 [k][n] -> bf16 hi/lo transposed [n][k] ----------------

__global__ __launch_bounds__(256) void wprep(const float* __restrict__ W, const float* __restrict__ Wo,
                                             ushort* __restrict__ WTh, ushort* __restrict__ WTl,
                                             ushort* __restrict__ WToh, ushort* __restrict__ WTol) {
  int i = blockIdx.x * 256 + threadIdx.x;   // 0..32767
  int j = i & 16383;
  int k = j >> 7, n = j & 127;
  float w = (i < 16384) ? W[j] : Wo[j];
  ushort h = f2bf(w);
  ushort lo = f2bf(w - bf2f(h));
  int o = n * 128 + k;
  if (i < 16384) { WTh[o] = h; WTl[o] = lo; }
  else           { WToh[o] = h; WTol[o] = lo; }
}

// ---------------- aggregation: CSR gather-sum, epilogue splits to bf16 hi/lo ----------------

__global__ __launch_bounds__(256) void aggregate(const float* __restrict__ y,
                                                 const int* __restrict__ rowptr,
                                                 const int* __restrict__ srcidx,
                                                 ushort* __restrict__ Ah, ushort* __restrict__ Al) {
  int grp  = (int)((blockIdx.x * 256 + threadIdx.x) >> 5);
  int lane = threadIdx.x & 31;
  if (grp >= NN) return;
  int beg = rowptr[grp], end = rowptr[grp + 1];
  float4 a0 = make_float4(0.f, 0.f, 0.f, 0.f);
  float4 a1 = make_float4(0.f, 0.f, 0.f, 0.f);
  int j = beg;
  for (; j + 2 <= end; j += 2) {
    int s0 = srcidx[j], s1 = srcidx[j + 1];
    float4 v0 = *(const float4*)(y + (size_t)s0 * DD + lane * 4);
    float4 v1 = *(const float4*)(y + (size_t)s1 * DD + lane * 4);
    a0.x += v0.x; a0.y += v0.y; a0.z += v0.z; a0.w += v0.w;
    a1.x += v1.x; a1.y += v1.y; a1.z += v1.z; a1.w += v1.w;
  }
  if (j < end) {
    int s0 = srcidx[j];
    float4 v0 = *(const float4*)(y + (size_t)s0 * DD + lane * 4);
    a0.x += v0.x; a0.y += v0.y; a0.z += v0.z; a0.w += v0.w;
  }
  float v[4] = {a0.x + a1.x, a0.y + a1.y, a0.z + a1.z, a0.w + a1.w};
  ushort h[4], l[4];
  #pragma unroll
  for (int r = 0; r < 4; ++r) { h[r] = f2bf(v[r]); l[r] = f2bf(v[r] - bf2f(h[r])); }
  uint2 hh, ll;
  hh.x = (uint)h[0] | ((uint)h[1] << 16); hh.y = (uint)h[2] | ((uint)h[3] << 16);
  ll.x = (uint)l[0] | ((uint)l[1] << 16); ll.y = (uint)l[2] | ((uint)l[3] << 16);
  *(uint2*)(Ah + (size_t)grp * DD + lane * 4) = hh;
  *(uint2*)(Al + (size_t)grp * DD + lane * 4) = ll;
}

// ---------------- GEMM: C[nrows,128] = act(A @ W + b) via bf16 MFMA, hi/lo split ----------------
// Block: 256 thr = 4 waves; wave w owns rows [blk*128 + w*32, +32), all 128 cols.
// K staged in two 64-k phases; WT hi/lo in LDS (16KB each), XOR-swizzled 16B chunks.
// MODE: 0 = fp32 out + ReLU, 1 = bf16 hi/lo out + ReLU (in-place on A is safe:
//        each wave reads/writes only its own 32-row slice), 2 = fp32 out, no ReLU.

template <int MODE>
__global__ __launch_bounds__(256, 3) void gemm_mfma(const ushort* Ah, const ushort* Al,
                                                    const ushort* __restrict__ Bh, const ushort* __restrict__ Bl,
                                                    const float* __restrict__ bias,
                                                    float* Cf, ushort* Ch, ushort* Cl, int nrows) {
  __shared__ ushort BHs[128 * 64];   // [n][64k] bf16, swizzled: 16KB
  __shared__ ushort BLs[128 * 64];
  int t = threadIdx.x;
  int w = t >> 6, l = t & 63;
  int lrow = l & 15, g = l >> 4;
  int m0 = blockIdx.x * 128 + w * 32;

  f32x4 acc[2][8];
  #pragma unroll
  for (int rt = 0; rt < 2; ++rt)
    #pragma unroll
    for (int ct = 0; ct < 8; ++ct) acc[rt][ct] = (f32x4){0.f, 0.f, 0.f, 0.f};

  #pragma unroll
  for (int p = 0; p < 2; ++p) {
    // stage WT k-half p into LDS (swizzle: byte_in_row ^= (n&7)<<4)
    #pragma unroll
    for (int i = 0; i < 4; ++i) {
      int c = t + i * 256;                 // 0..1023 chunks of 16B
      int n = c >> 3, k8 = c & 7;
      int gsrc = n * 128 + p * 64 + k8 * 8;                       // ushort idx
      int dsw  = n * 64 + (((k8 * 16) ^ ((n & 7) << 4)) >> 1);    // ushort idx
      *(uint4*)(&BHs[dsw]) = *(const uint4*)(Bh + gsrc);
      *(uint4*)(&BLs[dsw]) = *(const uint4*)(Bl + gsrc);
    }
    __syncthreads();

    #pragma unroll
    for (int kb = 0; kb < 2; ++kb) {
      int kgl = (p * 2 + kb) * 32 + g * 8;     // global k of this lane's 8-elem frag
      bf16x8 ah[2], al[2];
      #pragma unroll
      for (int rt = 0; rt < 2; ++rt) {
        int row = m0 + rt * 16 + lrow; if (row >= nrows) row = nrows - 1;
        ah[rt] = *(const bf16x8*)(Ah + (size_t)row * DD + kgl);
        al[rt] = *(const bf16x8*)(Al + (size_t)row * DD + kgl);
      }
      int kloc = kb * 64 + g * 16;             // byte offset within 128B k-half row
      int swz = (lrow & 7) << 4;
      #pragma unroll
      for (int ct = 0; ct < 8; ++ct) {
        int off = (ct * 16 + lrow) * 64 + ((kloc ^ swz) >> 1);    // ushort idx
        bf16x8 bh = *(const bf16x8*)(&BHs[off]);
        bf16x8 bl = *(const bf16x8*)(&BLs[off]);
        #pragma unroll
        for (int rt = 0; rt < 2; ++rt) {
          acc[rt][ct] = __builtin_amdgcn_mfma_f32_16x16x32_bf16(ah[rt], bh, acc[rt][ct], 0, 0, 0);
          acc[rt][ct] = __builtin_amdgcn_mfma_f32_16x16x32_bf16(ah[rt], bl, acc[rt][ct], 0, 0, 0);
          acc[rt][ct] = __builtin_amdgcn_mfma_f32_16x16x32_bf16(al[rt], bh, acc[rt][ct], 0, 0, 0);
        }
      }
    }
    __syncthreads();
  }

  // epilogue: C[row][col], row = m0 + rt*16 + g*4 + r, col = ct*16 + lrow  (m89 layout)
  float bb[8];
  #pragma unroll
  for (int ct = 0; ct < 8; ++ct) bb[ct] = bias[ct * 16 + lrow];
  #pragma unroll
  for (int rt = 0; rt < 2; ++rt) {
    #pragma unroll
    for (int r = 0; r < 4; ++r) {
      int row = m0 + rt * 16 + g * 4 + r;
      if (row < nrows) {
        #pragma unroll
        for (int ct = 0; ct < 8; ++ct) {
          float v = acc[rt][ct][r] + bb[ct];
          if (MODE != 2) v = fmaxf(v, 0.f);
          int col = ct * 16 + lrow;
          if (MODE == 1) {
            ushort h = f2bf(v);
            Ch[(size_t)row * DD + col] = h;
            Cl[(size_t)row * DD + col] = f2bf(v - bf2f(h));
          } else {
            Cf[(size_t)row * DD + col] = v;
          }
        }
      }
    }
  }
}

// ---------------- launch ----------------

extern "C" void kernel_launch(void* const* d_in, const int* in_sizes, int n_in,
                              void* d_out, int out_size, void* d_ws, size_t ws_size,
                              hipStream_t stream) {
  const float* x     = (const float*)d_in[0];
  const int*   ei    = (const int*)d_in[1];
  const float* W     = (const float*)d_in[2];
  const float* b     = (const float*)d_in[3];
  const float* W_out = (const float*)d_in[4];
  const float* b_out = (const float*)d_in[5];
  float*       out   = (float*)d_out;

  const int* src = ei;
  const int* dst = ei + NE;

  char* ws = (char*)d_ws;
  int*    rowptr = (int*)(ws + 0);            //  400128 B
  int*    cnt    = (int*)(ws + 400128);       //  400128 B
  int*    bsum   = (int*)(ws + 800256);       //    2048 B
  int*    srcidx = (int*)(ws + 802304);       // 2400000 B
  ushort* WTh    = (ushort*)(ws + 3202304);   //   32768 B
  ushort* WTl    = (ushort*)(ws + 3235072);
  ushort* WToh   = (ushort*)(ws + 3267840);
  ushort* WTol   = (ushort*)(ws + 3300608);
  ushort* Ahb    = (ushort*)(ws + 3333376);   // 25.6 MB bf16 hi
  ushort* Alb    = (ushort*)(ws + 28933376);  // 25.6 MB bf16 lo
  float*  yf     = (float*)(ws + 54533376);   // 51.2 MB fp32
  // total 105,733,376 B

  const int nb_scan = (NN + 1023) / 1024;     // 98

  zero_kernel<<<(NN + 255) / 256, 256, 0, stream>>>(cnt, NN);
  count_deg<<<(NE + 255) / 256, 256, 0, stream>>>(dst, cnt);
  scan_partial<<<nb_scan, 1024, 0, stream>>>(cnt, rowptr, bsum);
  scan_sums<<<1, 128, 0, stream>>>(bsum, nb_scan);
  scan_add<<<(NN + 255) / 256, 256, 0, stream>>>(rowptr, bsum);
  zero_kernel<<<(NN + 255) / 256, 256, 0, stream>>>(cnt, NN);
  fill_csr<<<(NE + 255) / 256, 256, 0, stream>>>(src, dst, rowptr, cnt, srcidx);
  wprep<<<128, 256, 0, stream>>>(W, W_out, WTh, WTl, WToh, WTol);

  const int aggBlocks  = (NN * 32 + 255) / 256;   // 12500
  const int gemmBlocks = (NN + 127) / 128;        // 782

  // layer 1
  aggregate<<<aggBlocks, 256, 0, stream>>>(x, rowptr, srcidx, Ahb, Alb);
  gemm_mfma<0><<<gemmBlocks, 256, 0, stream>>>(Ahb, Alb, WTh, WTl, b, yf, nullptr, nullptr, NN);
  // layer 2
  aggregate<<<aggBlocks, 256, 0, stream>>>(yf, rowptr, srcidx, Ahb, Alb);
  gemm_mfma<0><<<gemmBlocks, 256, 0, stream>>>(Ahb, Alb, WTh, WTl, b, yf, nullptr, nullptr, NN);
  // layer 3
  aggregate<<<aggBlocks, 256, 0, stream>>>(yf, rowptr, srcidx, Ahb, Alb);
  // in-place split output (each wave touches only its own 32-row slice)
  gemm_mfma<1><<<gemmBlocks, 256, 0, stream>>>(Ahb, Alb, WTh, WTl, b, nullptr, Ahb, Alb, NN);
  // output projection
  gemm_mfma<2><<<gemmBlocks, 256, 0, stream>>>(Ahb, Alb, WToh, WTol, b_out, out, nullptr, nullptr, NN);
}